// Round 4
// baseline (147.799 us; speedup 1.0000x reference)
//
#include <hip/hip_runtime.h>

#define BDIM 256
constexpr int Bn = 16, Cn = 4, Hn = 512, Wn = 512;
constexpr int SL   = Bn * Cn;          // 64 slices
constexpr int WPR  = Wn / 4;           // 128 int4/float4 words per row
constexpr int RPW  = 4;                // rows per wave
constexpr int RPB  = 16;               // rows per block (4 waves x 4 rows)
constexpr int CPB  = Hn / RPB;         // 32 chunks per slice
constexpr int NBLK = SL * CPB;         // 2048 blocks
constexpr float NTOT = 16777216.0f;    // B*C*H*W
constexpr float SMOOTHF = 0.0001f;

__device__ __forceinline__ float wave_reduce(float v) {
#pragma unroll
    for (int off = 32; off > 0; off >>= 1) v += __shfl_down(v, off);
    return v;
}

__device__ __forceinline__ unsigned pack4(int4 c) {
    return (unsigned)c.x | ((unsigned)c.y << 8) |
           ((unsigned)c.z << 16) | ((unsigned)c.w << 24);
}

// Deep-prologue streaming design. Evidence through round 3: VALUBusy pinned
// at 33% regardless of occupancy (35% or 55%) and warm-L3 replays no faster
// than cold -> each wave is ~90% blocked on s_waitcnt; per-row prefetch (4
// loads in flight) cannot cover ~200-900cy load latency with ~350cy of
// per-row compute. Fix: issue ALL 20 of a wave's 16B loads (12 gt int4 +
// 8 cmap float4, interleaved in consumption order) in one prologue burst,
// then compute 4 rows straight through on counted vmcnt(12/8/4/0) waits.
// One startup stall per wave, then pure compute. Costs ~80 VGPR of buffers
// -> launch_bounds(256,4) = 128 VGPR cap, 16 waves/CU. Rounds 1/3 proved
// occupancy beyond 16 waves/CU is worthless here; per-wave MLP is not.
// NO device-scope fences (round 2: agent-scope per-block fences = L2 flush,
// WRITE_SIZE 214 MB, 5x regression).
__global__ __launch_bounds__(BDIM, 4) void seg_main(const float4* __restrict__ cmap,
                                                    const int4* __restrict__ gt,
                                                    float* __restrict__ ws) {
    __shared__ float sm[5][4];

    const int tid   = threadIdx.x;
    const int lane  = tid & 63;
    const int wave  = tid >> 6;
    const int slice = blockIdx.x >> 5;        // / CPB
    const int chunk = blockIdx.x & (CPB - 1);
    const int R0    = chunk * RPB + wave * RPW;

    const float4* cm = cmap + slice * (Hn * WPR);
    const int4*   gs = gt   + slice * (Hn * WPR);
    const int wi = 2 * lane;                  // this lane: words wi, wi+1 (elems 8l..8l+7)

    // ---- prologue: issue all 20 loads, ordered by first consumption ----
    // gt rows staged: array row j <-> gt row R0-1+j, j = 0..5
    int4 g[12];
    float4 xf[8];
    {
        const int rm = max(R0 - 1, 0);
        g[0]  = gs[rm * WPR + wi];
        g[1]  = gs[rm * WPR + wi + 1];
        g[2]  = gs[R0 * WPR + wi];
        g[3]  = gs[R0 * WPR + wi + 1];
        g[4]  = gs[(R0 + 1) * WPR + wi];      // R0+1 <= 509, always valid
        g[5]  = gs[(R0 + 1) * WPR + wi + 1];
        xf[0] = cm[R0 * WPR + wi];
        xf[1] = cm[R0 * WPR + wi + 1];
        g[6]  = gs[(R0 + 2) * WPR + wi];      // <= 510
        g[7]  = gs[(R0 + 2) * WPR + wi + 1];
        xf[2] = cm[(R0 + 1) * WPR + wi];
        xf[3] = cm[(R0 + 1) * WPR + wi + 1];
        g[8]  = gs[(R0 + 3) * WPR + wi];      // <= 511
        g[9]  = gs[(R0 + 3) * WPR + wi + 1];
        xf[4] = cm[(R0 + 2) * WPR + wi];
        xf[5] = cm[(R0 + 2) * WPR + wi + 1];
        const int rl = min(R0 + 4, Hn - 1);
        g[10] = gs[rl * WPR + wi];
        g[11] = gs[rl * WPR + wi + 1];
        xf[6] = cm[(R0 + 3) * WPR + wi];
        xf[7] = cm[(R0 + 3) * WPR + wi + 1];
    }

    // pack first three gt rows (up / center / down for output row R0)
    unsigned u0 = pack4(g[0]), u1 = pack4(g[1]);
    if (R0 == 0) { u0 = 0u; u1 = 0u; }
    unsigned c0 = pack4(g[2]), c1 = pack4(g[3]);
    unsigned d0 = pack4(g[4]), d1 = pack4(g[5]);

    float cesum = 0.f, cxy = 0.f, ed = 0.f, inter = 0.f, jsum = 0.f;
    int icnt = 0;

#pragma unroll
    for (int k = 0; k < RPW; ++k) {
        // horizontal neighbors: intra-wave shfl; lane edges are the zero pad
        unsigned pw = __shfl_up(c1, 1);   if (lane == 0)  pw = 0u;
        unsigned nw = __shfl_down(c0, 1); if (lane == 63) nw = 0u;

        const unsigned l0 = (c0 << 8) | (pw >> 24);
        const unsigned r0 = (c0 >> 8) | ((c1 & 0xffu) << 24);
        const unsigned l1 = (c1 << 8) | (c0 >> 24);
        const unsigned r1 = (c1 >> 8) | (nw << 24);

        // bytes are 0/1: dilation = bitwise OR, erosion = bitwise AND
        const unsigned ew0 = (c0 | u0 | d0 | l0 | r0) & ~(c0 & u0 & d0 & l0 & r0);
        const unsigned ew1 = (c1 | u1 | d1 | l1 | r1) & ~(c1 & u1 & d1 & l1 & r1);
        icnt += __popc(c0) + __popc(c1);

        const float4 x0 = xf[2 * k];
        const float4 x1 = xf[2 * k + 1];
        const float xs[8] = {x0.x, x0.y, x0.z, x0.w, x1.x, x1.y, x1.z, x1.w};
#pragma unroll
        for (int e = 0; e < 8; ++e) {
            const unsigned cw = (e < 4) ? c0 : c1;
            const unsigned ew = (e < 4) ? ew0 : ew1;
            const int sh = 8 * (e & 3);
            const float xv = xs[e];
            const float t  = __expf(-fabsf(xv));            // exp(-|x|)
            const float u  = 1.f + t;
            const float sp = fmaxf(xv, 0.f) + __logf(u);    // softplus = logaddexp(0,x)
            const float rc = __builtin_amdgcn_rcpf(u);
            const float pred = (xv >= 0.f) ? rc : t * rc;   // sigmoid(x)
            const float yf = (float)((cw >> sh) & 1u);
            const float eb = (float)((ew >> sh) & 1u);

            cesum += sp;
            cxy   = fmaf(yf, xv, cxy);                      // ce = cesum - cxy
            inter = fmaf(yf, pred, inter);
            jsum += pred;
            ed    = fmaf(eb, fminf(sp, 100.f), ed);         // edge loss term
        }

        // roll vertical window; pack next down-row (gt row R0+k+2)
        if (k < RPW - 1) {
            u0 = c0; u1 = c1; c0 = d0; c1 = d1;
            unsigned t0 = pack4(g[2 * k + 6]), t1 = pack4(g[2 * k + 7]);
            if (R0 + k + 2 >= Hn) { t0 = 0u; t1 = 0u; }
            d0 = t0; d1 = t1;
        }
    }

    // ---- block reduction, one write per partial, no atomics ----
    const float v0 = wave_reduce(cesum - cxy);
    const float v1 = wave_reduce(ed);
    const float v2 = wave_reduce(inter);
    const float v3 = wave_reduce((float)icnt);
    const float v4 = wave_reduce(jsum);
    if (lane == 0) {
        sm[0][wave] = v0; sm[1][wave] = v1; sm[2][wave] = v2;
        sm[3][wave] = v3; sm[4][wave] = v4;
    }
    __syncthreads();
    if (tid < 5)
        ws[tid * NBLK + blockIdx.x] = sm[tid][0] + sm[tid][1] + sm[tid][2] + sm[tid][3];
}

__global__ void seg_finish(const float* __restrict__ ws, float* __restrict__ out) {
    const int t = threadIdx.x;                // 64 threads, one per (b,c) slice
    float ce = 0.f, ed = 0.f, inter = 0.f, is = 0.f, js = 0.f;
#pragma unroll 8
    for (int i = 0; i < CPB; ++i) {
        const int b = t * CPB + i;
        ce    += ws[0 * NBLK + b];
        ed    += ws[1 * NBLK + b];
        inter += ws[2 * NBLK + b];
        is    += ws[3 * NBLK + b];
        js    += ws[4 * NBLK + b];
    }
    const float score = (2.f * inter + SMOOTHF) / (is + js + SMOOTHF);
    float dice = (1.f - score) * (1.f / (float)Bn);   // mean over batch
    dice = wave_reduce(dice);                         // sum over classes (64 slices)
    ce = wave_reduce(ce);
    ed = wave_reduce(ed);
    if (t == 0)
        out[0] = ce * (1.f / NTOT) + ed * (1.f / NTOT) + dice;
}

extern "C" void kernel_launch(void* const* d_in, const int* in_sizes, int n_in,
                              void* d_out, int out_size, void* d_ws, size_t ws_size,
                              hipStream_t stream) {
    const float4* cmap = (const float4*)d_in[0];
    const int4*   gt   = (const int4*)d_in[1];
    float* ws = (float*)d_ws;                 // 5 * 2048 floats, fully rewritten
    seg_main<<<NBLK, BDIM, 0, stream>>>(cmap, gt, ws);
    seg_finish<<<1, 64, 0, stream>>>(ws, (float*)d_out);
}

// Round 5
// 146.378 us; speedup vs baseline: 1.0097x; 1.0097x over previous
//
#include <hip/hip_runtime.h>

#define BDIM 256
constexpr int Bn = 16, Cn = 4, Hn = 512, Wn = 512;
constexpr int SL   = Bn * Cn;          // 64 slices
constexpr int WPR  = Wn / 4;           // 128 int4/float4 words per row
constexpr int RPW  = 4;                // rows per wave
constexpr int RPB  = 16;               // rows per block (4 waves x 4 rows)
constexpr int CPB  = Hn / RPB;         // 32 chunks per slice
constexpr int NBLK = SL * CPB;         // 2048 blocks
constexpr float NTOT = 16777216.0f;    // B*C*H*W
constexpr float SMOOTHF = 0.0001f;

__device__ __forceinline__ float wave_reduce(float v) {
#pragma unroll
    for (int off = 32; off > 0; off >>= 1) v += __shfl_down(v, off);
    return v;
}

__device__ __forceinline__ unsigned pack4(int4 c) {
    return (unsigned)c.x | ((unsigned)c.y << 8) |
           ((unsigned)c.z << 16) | ((unsigned)c.w << 24);
}

// Deep-prologue streaming design, round 5: same as round 4 BUT with a
// compiler fence between the 20-load prologue and the compute body.
// Round-4 evidence: VGPR_Count=32 proved hipcc re-sank the prologue loads
// to sit directly before their uses (register-pressure heuristic), killing
// MLP -> VALUBusy stuck at 33%, 46 us. The fence (asm memory clobber +
// sched_barrier(0)) makes sinking illegal: all 20 16B loads must ISSUE
// before any compute, results stay live (~80 VGPR), and the compiler then
// emits counted vmcnt(N) waits per consumption group. One pipeline fill
// per wave instead of ~10 serialized stalls.
// launch_bounds(256,4) = 128 VGPR cap -> 16 waves/CU; rounds 1/3 showed
// occupancy >16 waves/CU buys nothing here, per-wave MLP is what's missing.
// NO device-scope fences (round 2: per-block agent-scope fence = L2 flush,
// WRITE_SIZE 214 MB, 5x regression).
__global__ __launch_bounds__(BDIM, 4) void seg_main(const float4* __restrict__ cmap,
                                                    const int4* __restrict__ gt,
                                                    float* __restrict__ ws) {
    __shared__ float sm[5][4];

    const int tid   = threadIdx.x;
    const int lane  = tid & 63;
    const int wave  = tid >> 6;
    const int slice = blockIdx.x >> 5;        // / CPB
    const int chunk = blockIdx.x & (CPB - 1);
    const int R0    = chunk * RPB + wave * RPW;

    const float4* cm = cmap + slice * (Hn * WPR);
    const int4*   gs = gt   + slice * (Hn * WPR);
    const int wi = 2 * lane;                  // this lane: words wi, wi+1 (elems 8l..8l+7)

    // ---- prologue: issue all 20 loads back-to-back ----
    // gt rows staged: g[2j],g[2j+1] <-> gt row R0-1+j, j = 0..5
    int4 g[12];
    float4 xf[8];
    {
        const int rm = max(R0 - 1, 0);
        g[0]  = gs[rm * WPR + wi];
        g[1]  = gs[rm * WPR + wi + 1];
        g[2]  = gs[R0 * WPR + wi];
        g[3]  = gs[R0 * WPR + wi + 1];
        g[4]  = gs[(R0 + 1) * WPR + wi];      // R0+1 <= 509, always valid
        g[5]  = gs[(R0 + 1) * WPR + wi + 1];
        xf[0] = cm[R0 * WPR + wi];
        xf[1] = cm[R0 * WPR + wi + 1];
        g[6]  = gs[(R0 + 2) * WPR + wi];      // <= 510
        g[7]  = gs[(R0 + 2) * WPR + wi + 1];
        xf[2] = cm[(R0 + 1) * WPR + wi];
        xf[3] = cm[(R0 + 1) * WPR + wi + 1];
        g[8]  = gs[(R0 + 3) * WPR + wi];      // <= 511
        g[9]  = gs[(R0 + 3) * WPR + wi + 1];
        xf[4] = cm[(R0 + 2) * WPR + wi];
        xf[5] = cm[(R0 + 2) * WPR + wi + 1];
        const int rl = min(R0 + 4, Hn - 1);
        g[10] = gs[rl * WPR + wi];
        g[11] = gs[rl * WPR + wi + 1];
        xf[6] = cm[(R0 + 3) * WPR + wi];
        xf[7] = cm[(R0 + 3) * WPR + wi + 1];
    }
    // Fence: loads cannot sink past a memory-clobber asm; compute cannot be
    // scheduled above sched_barrier(0). Forces all 20 loads in flight here.
    asm volatile("" ::: "memory");
    __builtin_amdgcn_sched_barrier(0);

    // pack first three gt rows (up / center / down for output row R0)
    unsigned u0 = pack4(g[0]), u1 = pack4(g[1]);
    if (R0 == 0) { u0 = 0u; u1 = 0u; }
    unsigned c0 = pack4(g[2]), c1 = pack4(g[3]);
    unsigned d0 = pack4(g[4]), d1 = pack4(g[5]);

    float cesum = 0.f, cxy = 0.f, ed = 0.f, inter = 0.f, jsum = 0.f;
    int icnt = 0;

#pragma unroll
    for (int k = 0; k < RPW; ++k) {
        // horizontal neighbors: intra-wave shfl; lane edges are the zero pad
        unsigned pw = __shfl_up(c1, 1);   if (lane == 0)  pw = 0u;
        unsigned nw = __shfl_down(c0, 1); if (lane == 63) nw = 0u;

        const unsigned l0 = (c0 << 8) | (pw >> 24);
        const unsigned r0 = (c0 >> 8) | ((c1 & 0xffu) << 24);
        const unsigned l1 = (c1 << 8) | (c0 >> 24);
        const unsigned r1 = (c1 >> 8) | (nw << 24);

        // bytes are 0/1: dilation = bitwise OR, erosion = bitwise AND
        const unsigned ew0 = (c0 | u0 | d0 | l0 | r0) & ~(c0 & u0 & d0 & l0 & r0);
        const unsigned ew1 = (c1 | u1 | d1 | l1 | r1) & ~(c1 & u1 & d1 & l1 & r1);
        icnt += __popc(c0) + __popc(c1);

        const float4 x0 = xf[2 * k];
        const float4 x1 = xf[2 * k + 1];
        const float xs[8] = {x0.x, x0.y, x0.z, x0.w, x1.x, x1.y, x1.z, x1.w};
#pragma unroll
        for (int e = 0; e < 8; ++e) {
            const unsigned cw = (e < 4) ? c0 : c1;
            const unsigned ew = (e < 4) ? ew0 : ew1;
            const int sh = 8 * (e & 3);
            const float xv = xs[e];
            const float t  = __expf(-fabsf(xv));            // exp(-|x|)
            const float u  = 1.f + t;
            const float sp = fmaxf(xv, 0.f) + __logf(u);    // softplus = logaddexp(0,x)
            const float rc = __builtin_amdgcn_rcpf(u);
            const float pred = (xv >= 0.f) ? rc : t * rc;   // sigmoid(x)
            const float yf = (float)((cw >> sh) & 1u);
            const float eb = (float)((ew >> sh) & 1u);

            cesum += sp;
            cxy   = fmaf(yf, xv, cxy);                      // ce = cesum - cxy
            inter = fmaf(yf, pred, inter);
            jsum += pred;
            ed    = fmaf(eb, fminf(sp, 100.f), ed);         // edge loss term
        }

        // roll vertical window; pack next down-row (gt row R0+k+2)
        if (k < RPW - 1) {
            u0 = c0; u1 = c1; c0 = d0; c1 = d1;
            unsigned t0 = pack4(g[2 * k + 6]), t1 = pack4(g[2 * k + 7]);
            if (R0 + k + 2 >= Hn) { t0 = 0u; t1 = 0u; }
            d0 = t0; d1 = t1;
        }
    }

    // ---- block reduction, one write per partial, no atomics ----
    const float v0 = wave_reduce(cesum - cxy);
    const float v1 = wave_reduce(ed);
    const float v2 = wave_reduce(inter);
    const float v3 = wave_reduce((float)icnt);
    const float v4 = wave_reduce(jsum);
    if (lane == 0) {
        sm[0][wave] = v0; sm[1][wave] = v1; sm[2][wave] = v2;
        sm[3][wave] = v3; sm[4][wave] = v4;
    }
    __syncthreads();
    if (tid < 5)
        ws[tid * NBLK + blockIdx.x] = sm[tid][0] + sm[tid][1] + sm[tid][2] + sm[tid][3];
}

__global__ void seg_finish(const float* __restrict__ ws, float* __restrict__ out) {
    const int t = threadIdx.x;                // 64 threads, one per (b,c) slice
    float ce = 0.f, ed = 0.f, inter = 0.f, is = 0.f, js = 0.f;
#pragma unroll 8
    for (int i = 0; i < CPB; ++i) {
        const int b = t * CPB + i;
        ce    += ws[0 * NBLK + b];
        ed    += ws[1 * NBLK + b];
        inter += ws[2 * NBLK + b];
        is    += ws[3 * NBLK + b];
        js    += ws[4 * NBLK + b];
    }
    const float score = (2.f * inter + SMOOTHF) / (is + js + SMOOTHF);
    float dice = (1.f - score) * (1.f / (float)Bn);   // mean over batch
    dice = wave_reduce(dice);                         // sum over classes (64 slices)
    ce = wave_reduce(ce);
    ed = wave_reduce(ed);
    if (t == 0)
        out[0] = ce * (1.f / NTOT) + ed * (1.f / NTOT) + dice;
}

extern "C" void kernel_launch(void* const* d_in, const int* in_sizes, int n_in,
                              void* d_out, int out_size, void* d_ws, size_t ws_size,
                              hipStream_t stream) {
    const float4* cmap = (const float4*)d_in[0];
    const int4*   gt   = (const int4*)d_in[1];
    float* ws = (float*)d_ws;                 // 5 * 2048 floats, fully rewritten
    seg_main<<<NBLK, BDIM, 0, stream>>>(cmap, gt, ws);
    seg_finish<<<1, 64, 0, stream>>>(ws, (float*)d_out);
}